// Round 2
// baseline (5051.009 us; speedup 1.0000x reference)
//
#include <hip/hip_runtime.h>
#include <cstdint>

#define B_SZ   2048
#define T_SZ   80
#define VOCABN 80
#define EMBN   8
#define HID    256
#define G4     1024
#define TILE   16
#define NBLK   (B_SZ / TILE)   // 128
#define NWAVE  8
#define NTHR   (NWAVE * 64)    // 512

typedef __bf16 bf16;
typedef __attribute__((ext_vector_type(8))) __bf16 bf16x8;
typedef __attribute__((ext_vector_type(4))) float  f32x4;

__device__ __forceinline__ float sigf(float x)   { return 1.0f / (1.0f + __expf(-x)); }
__device__ __forceinline__ float tanhf2(float x) { return 1.0f - 2.0f / (__expf(2.0f * x) + 1.0f); }

__device__ __forceinline__ unsigned short f2bf(float f) {
    union { float f; unsigned int u; } v; v.f = f;
    unsigned int u = v.u;
    return (unsigned short)((u + 0x7FFFu + ((u >> 16) & 1u)) >> 16);
}

// Swizzled h-tile addressing: row-major [16][256] bf16, 512B rows, 16B blocks
// rotated by 2*row within the row -> even bank spread for ds_read_b128.
__device__ __forceinline__ int hswz(int row, int col) {
    return row * 256 + ((((col >> 3) + 2 * row) & 31) << 3) + (col & 7);
}

// LDS-consistency barrier WITHOUT vmcnt drain (keeps weight prefetch in flight).
__device__ __forceinline__ void barrier_lds() {
    __builtin_amdgcn_sched_barrier(0);
    asm volatile("s_waitcnt lgkmcnt(0)" ::: "memory");
    __builtin_amdgcn_s_barrier();
    __builtin_amdgcn_sched_barrier(0);
}

// ---------------- prep kernels (unchanged, proven correct) ----------------
__global__ void prep_eg(const float* __restrict__ emb, const float* __restrict__ W1,
                        const float* __restrict__ b1, float* __restrict__ eg) {
    int idx = blockIdx.x * blockDim.x + threadIdx.x;
    if (idx >= VOCABN * G4) return;
    int v = idx >> 10, n = idx & 1023;
    float s = b1[n];
#pragma unroll
    for (int e = 0; e < EMBN; ++e) s += emb[v * EMBN + e] * W1[e * G4 + n];
    eg[idx] = s;
}

__global__ void prep_w1(const float* __restrict__ W1, unsigned short* __restrict__ w1p) {
    int idx = blockIdx.x * blockDim.x + threadIdx.x;     // nt(64) x k(8) x lane(64)
    if (idx >= 64 * 8 * 64) return;
    int lane = idx & 63, k = (idx >> 6) & 7, nt = idx >> 9;
    int scol = (nt << 4) + (lane & 15);
    int r0 = EMBN + k * 32 + ((lane >> 4) << 3);
#pragma unroll
    for (int e = 0; e < 8; ++e)
        w1p[idx * 8 + e] = f2bf(W1[(r0 + e) * G4 + scol]);
}

__global__ void prep_w2(const float* __restrict__ W2, unsigned short* __restrict__ w2p) {
    int idx = blockIdx.x * blockDim.x + threadIdx.x;     // nt(64) x k(16) x lane(64)
    if (idx >= 64 * 16 * 64) return;
    int lane = idx & 63, k = (idx >> 6) & 15, nt = idx >> 10;
    int scol = (nt << 4) + (lane & 15);
    int r0 = k * 32 + ((lane >> 4) << 3);
#pragma unroll
    for (int e = 0; e < 8; ++e)
        w2p[idx * 8 + e] = f2bf(W2[(r0 + e) * G4 + scol]);
}

// ---------------- fused 2-layer LSTM + loss ----------------
// Weight pair loads: pair (g) = tiles nt = g*16 + 2*wid + {0,1}.
#define L1LOAD(nb, g) do {                                                      \
    const bf16x8* bp_ = w1v + (size_t)((g) * 16 + 2 * wid) * 512 + lane;        \
    _Pragma("unroll")                                                           \
    for (int k_ = 0; k_ < 8; ++k_) {                                            \
        wb[nb][0][k_] = bp_[k_ * 64];                                           \
        wb[nb][1][k_] = bp_[512 + k_ * 64];                                     \
    }                                                                           \
} while (0)

#define L2LOAD(nb, g, half) do {                                                \
    const bf16x8* bp_ = w2v + (size_t)((g) * 16 + 2 * wid) * 1024               \
                        + (half) * 512 + lane;                                  \
    _Pragma("unroll")                                                           \
    for (int k_ = 0; k_ < 8; ++k_) {                                            \
        wb[nb][0][k_] = bp_[k_ * 64];                                           \
        wb[nb][1][k_] = bp_[1024 + k_ * 64];                                    \
    }                                                                           \
} while (0)

#define PAIRMM(nb, g) do {                                                      \
    _Pragma("unroll")                                                           \
    for (int k_ = 0; k_ < 8; ++k_) {                                            \
        acc[g][0] = __builtin_amdgcn_mfma_f32_16x16x32_bf16(afr[k_], wb[nb][0][k_], acc[g][0], 0, 0, 0); \
        acc[g][1] = __builtin_amdgcn_mfma_f32_16x16x32_bf16(afr[k_], wb[nb][1][k_], acc[g][1], 0, 0, 0); \
    }                                                                           \
} while (0)

#define LOADA(hptr) do {                                                        \
    _Pragma("unroll")                                                           \
    for (int k_ = 0; k_ < 8; ++k_)                                              \
        afr[k_] = *(const bf16x8*)&(hptr)[lc * 256 + (((4 * k_ + lg + 2 * lc) & 31) << 3)]; \
} while (0)

__global__ __launch_bounds__(NTHR, 2)
void lstm_fused(const int* __restrict__ feat, const int* __restrict__ labels,
                const float* __restrict__ eg,
                const unsigned short* __restrict__ w1p,
                const unsigned short* __restrict__ w2p,
                const float* __restrict__ b2,
                const float* __restrict__ Wd, const float* __restrict__ bd,
                float* __restrict__ out)
{
    __shared__ __align__(16) bf16 h1s[2][TILE * 256];
    __shared__ __align__(16) bf16 h2s[2][TILE * 256];
    __shared__ int   toks[TILE][T_SZ];
    __shared__ float logitb[TILE][VOCABN + 4];
    __shared__ float lossb[TILE];

    const int tid  = threadIdx.x;
    const int lane = tid & 63;
    const int wid  = tid >> 6;     // wave 0..7 owns gate-cols pairs (2*wid, 2*wid+1) per gate
    const int lc   = lane & 15;
    const int lg   = lane >> 4;
    const int b0   = blockIdx.x * TILE;

    for (int i = tid; i < TILE * 256; i += NTHR) {
        h1s[0][i] = (bf16)0.0f;
        h2s[0][i] = (bf16)0.0f;
    }
    for (int i = tid; i < TILE * T_SZ; i += NTHR) {
        int r = i / T_SZ, t = i - r * T_SZ;
        toks[r][t] = feat[(b0 + r) * T_SZ + t];
    }
    __syncthreads();

    const bf16x8* w1v = (const bf16x8*)w1p;
    const bf16x8* w2v = (const bf16x8*)w2p;

    const f32x4 zf = {0.f, 0.f, 0.f, 0.f};
    f32x4 c1[2], c2[2];
    c1[0] = zf; c1[1] = zf; c2[0] = zf; c2[1] = zf;

    float b2r[4][2];
#pragma unroll
    for (int g = 0; g < 4; ++g)
#pragma unroll
        for (int d = 0; d < 2; ++d)
            b2r[g][d] = b2[g * 256 + wid * 32 + d * 16 + lc];

    bf16x8 wb[2][2][8];
    bf16x8 afr[8];
    f32x4 acc[4][2];

    L1LOAD(0, 0);   // prime the pipeline

    for (int t = 0; t < T_SZ; ++t) {
        const int p = t & 1, q = p ^ 1;
        bf16* h1p = h1s[p]; bf16* h1q = h1s[q];
        bf16* h2p = h2s[p]; bf16* h2q = h2s[q];

        // =================== layer 1 ===================
#pragma unroll
        for (int g = 0; g < 4; ++g) { acc[g][0] = zf; acc[g][1] = zf; }
        LOADA(h1p);
        L1LOAD(1, 1);       PAIRMM(0, 0);
        L1LOAD(0, 2);       PAIRMM(1, 1);
        L1LOAD(1, 3);       PAIRMM(0, 2);
        L2LOAD(0, 0, 0);    PAIRMM(1, 3);   // prefetch L2 pair across barrier

        float egv[4][2][4];
#pragma unroll
        for (int d2 = 0; d2 < 2; ++d2)
#pragma unroll
            for (int r = 0; r < 4; ++r) {
                const int row = lg * 4 + r;
                const int tok = toks[row][t];
                const float* e = eg + tok * G4 + wid * 32 + d2 * 16 + lc;
                egv[0][d2][r] = e[0];
                egv[1][d2][r] = e[256];
                egv[2][d2][r] = e[512];
                egv[3][d2][r] = e[768];
            }

#pragma unroll
        for (int d2 = 0; d2 < 2; ++d2) {
            const int hcol = wid * 32 + d2 * 16 + lc;
#pragma unroll
            for (int r = 0; r < 4; ++r) {
                const int row = lg * 4 + r;
                float gi = acc[0][d2][r] + egv[0][d2][r];
                float gj = acc[1][d2][r] + egv[1][d2][r];
                float gf = acc[2][d2][r] + egv[2][d2][r];
                float go = acc[3][d2][r] + egv[3][d2][r];
                float cn = c1[d2][r] * sigf(gf + 1.0f) + sigf(gi) * tanhf2(gj);
                float h  = tanhf2(cn) * sigf(go);
                c1[d2][r] = cn;
                h1q[hswz(row, hcol)] = (bf16)h;
            }
        }
        barrier_lds();

        // =================== layer 2 ===================
#pragma unroll
        for (int g = 0; g < 4; ++g) { acc[g][0] = zf; acc[g][1] = zf; }
        LOADA(h1q);                          // x-part fragments (new h1)
        L2LOAD(1, 1, 0);    PAIRMM(0, 0);
        L2LOAD(0, 2, 0);    PAIRMM(1, 1);
        L2LOAD(1, 3, 0);    PAIRMM(0, 2);
        L2LOAD(0, 0, 1);    PAIRMM(1, 3);
        LOADA(h2p);                          // h-part fragments (old h2)
        L2LOAD(1, 1, 1);    PAIRMM(0, 0);
        L2LOAD(0, 2, 1);    PAIRMM(1, 1);
        L2LOAD(1, 3, 1);    PAIRMM(0, 2);
        L1LOAD(0, 0);       PAIRMM(1, 3);   // prefetch next step's L1 pair 0

#pragma unroll
        for (int d2 = 0; d2 < 2; ++d2) {
            const int hcol = wid * 32 + d2 * 16 + lc;
#pragma unroll
            for (int r = 0; r < 4; ++r) {
                const int row = lg * 4 + r;
                float gi = acc[0][d2][r] + b2r[0][d2];
                float gj = acc[1][d2][r] + b2r[1][d2];
                float gf = acc[2][d2][r] + b2r[2][d2];
                float go = acc[3][d2][r] + b2r[3][d2];
                float cn = c2[d2][r] * sigf(gf + 1.0f) + sigf(gi) * tanhf2(gj);
                float h  = tanhf2(cn) * sigf(go);
                c2[d2][r] = cn;
                h2q[hswz(row, hcol)] = (bf16)h;
            }
        }
        barrier_lds();
    }

    // ---- epilogue: logits = h2_last @ Wd + bd, log-softmax NLL, mean ----
    // T_SZ=80 even -> final h2 buffer index 0.
    const bf16* h2fin = h2s[0];
    for (int pp = tid; pp < TILE * VOCABN; pp += NTHR) {
        int row = pp / VOCABN, v = pp - row * VOCABN;
        float s = bd[v];
        for (int k = 0; k < HID; ++k)
            s += (float)h2fin[hswz(row, k)] * Wd[k * VOCABN + v];
        logitb[row][v] = s;
    }
    __syncthreads();
    if (tid < TILE) {
        const int row = tid;
        float m = -1e30f;
        for (int v = 0; v < VOCABN; ++v) m = fmaxf(m, logitb[row][v]);
        float s = 0.f;
        for (int v = 0; v < VOCABN; ++v) s += __expf(logitb[row][v] - m);
        int lab = labels[b0 + row];
        lossb[row] = m + __logf(s) - logitb[row][lab];
    }
    __syncthreads();
    if (tid == 0) {
        float s = 0.f;
#pragma unroll
        for (int r = 0; r < TILE; ++r) s += lossb[r];
        atomicAdd(out, s * (1.0f / (float)B_SZ));
    }
}

extern "C" void kernel_launch(void* const* d_in, const int* in_sizes, int n_in,
                              void* d_out, int out_size, void* d_ws, size_t ws_size,
                              hipStream_t stream)
{
    (void)in_sizes; (void)n_in; (void)out_size; (void)ws_size;
    const int*   feat   = (const int*)d_in[0];
    const int*   labels = (const int*)d_in[1];
    const float* emb    = (const float*)d_in[2];
    const float* W1     = (const float*)d_in[3];
    const float* b1     = (const float*)d_in[4];
    const float* W2     = (const float*)d_in[5];
    const float* b2     = (const float*)d_in[6];
    const float* Wd     = (const float*)d_in[7];
    const float* bd     = (const float*)d_in[8];
    float* out = (float*)d_out;

    char* ws = (char*)d_ws;
    float*          eg  = (float*)ws;                               // 327680 B
    unsigned short* w1p = (unsigned short*)(ws + 327680);           // 524288 B
    unsigned short* w2p = (unsigned short*)(ws + 327680 + 524288);  // 1048576 B

    hipMemsetAsync(d_out, 0, sizeof(float), stream);
    prep_eg<<<(VOCABN * G4 + 255) / 256, 256, 0, stream>>>(emb, W1, b1, eg);
    prep_w1<<<(64 * 8 * 64) / 256, 256, 0, stream>>>(W1, w1p);
    prep_w2<<<(64 * 16 * 64) / 256, 256, 0, stream>>>(W2, w2p);
    lstm_fused<<<NBLK, NTHR, 0, stream>>>(feat, labels, eg, w1p, w2p, b2, Wd, bd, out);
}